// Round 3
// baseline (419.902 us; speedup 1.0000x reference)
//
#include <hip/hip_runtime.h>

#define NDIR  6
#define B_    16
#define N_IN  16384
#define N_OUT 8192
#define IDIM  128
#define ODIM  128
#define TOTAL (B_ * N_OUT)   // 131072 nodes
#define BM    128            // nodes per block
#define BK    32             // K chunk (of 256)

// d_ws layout (ints): [0..7]=cnt, [8..14]=offsets, [16..23]=cursors, ids at 64
#define WS_CNT 0
#define WS_OFF 8
#define WS_CUR 16
#define WS_IDS 64

__global__ void zero_kernel(int* ws) {
    int t = threadIdx.x;
    if (t < 32) ws[t] = 0;
}

__global__ void count_kernel(const int* __restrict__ vec, const int* __restrict__ dmap,
                             int* __restrict__ ws) {
    __shared__ int h[NDIR];
    int t = threadIdx.x;
    if (t < NDIR) h[t] = 0;
    __syncthreads();
    int id = blockIdx.x * 256 + t;
    if (id < TOTAL) {
        int d = dmap[vec[id]];
        atomicAdd(&h[d], 1);
    }
    __syncthreads();
    if (t < NDIR && h[t]) atomicAdd(&ws[WS_CNT + t], h[t]);
}

__global__ void prefix_kernel(int* ws) {
    if (threadIdx.x == 0) {
        int acc = 0;
        for (int i = 0; i < NDIR; ++i) {
            ws[WS_OFF + i] = acc;
            ws[WS_CUR + i] = acc;
            acc += ws[WS_CNT + i];
        }
        ws[WS_OFF + NDIR] = acc;
    }
}

__global__ void scatter_kernel(const int* __restrict__ vec, const int* __restrict__ dmap,
                               int* __restrict__ ws) {
    __shared__ int h[NDIR];
    __shared__ int base[NDIR];
    int t = threadIdx.x;
    if (t < NDIR) h[t] = 0;
    __syncthreads();
    int id = blockIdx.x * 256 + t;
    int d = 0, pos = 0;
    if (id < TOTAL) {
        d = dmap[vec[id]];
        pos = atomicAdd(&h[d], 1);
    }
    __syncthreads();
    if (t < NDIR) base[t] = h[t] ? atomicAdd(&ws[WS_CUR + t], h[t]) : 0;
    __syncthreads();
    if (id < TOTAL) ws[WS_IDS + base[d] + pos] = id;
}

// A tile: [BM][32] floats, XOR-chunk swizzled: element (m,k) lives at
//   m*32 + (((k>>2) ^ ((m>>3)&3))<<2) + (k&3)
// -> a wave's 4 distinct rows (m = ng*8+c, ng&3 distinct) hit 4 distinct
//    4-bank groups: conflict-free.
// W tile: [32][164] floats with +4-float skew per 16 cols: (r,c) at
//   r*164 + c + ((c>>4)<<2)
// -> the 16 og-chunks (32B each) cover all 8 bank slots exactly twice.
#define WSTRIDE 164
__device__ __forceinline__ int a_ofs(int m, int k) {
    return m * 32 + ((((k >> 2) ^ ((m >> 3) & 3)) << 2) | (k & 3));
}
__device__ __forceinline__ int w_ofs(int r, int c) {
    return r * WSTRIDE + c + ((c >> 4) << 2);
}

__global__ __launch_bounds__(256, 4) void gemm_kernel(
    const float* __restrict__ last, const float* __restrict__ W,
    const float* __restrict__ bias, const float* __restrict__ alphap,
    const int* __restrict__ vec, const int* __restrict__ drev,
    const int* __restrict__ child_l, const int* __restrict__ child_r,
    const int* __restrict__ ws, float* __restrict__ out)
{
    int dir = blockIdx.y;
    int start = ws[WS_OFF + dir];
    int end   = ws[WS_OFF + dir + 1];
    int m0 = start + (int)blockIdx.x * BM;
    if (m0 >= end) return;
    const int* ids = ws + WS_IDS;

    __shared__ int   s_row0[BM], s_row1[BM];
    __shared__ float As[BM * 32];
    __shared__ float Wl[BK * WSTRIDE];

    int t = threadIdx.x;
    if (t < BM) {
        int idx = m0 + t;
        bool valid = idx < end;
        int id = ids[valid ? idx : end - 1];
        int b = id >> 13;            // N_OUT = 8192
        int n = id & (N_OUT - 1);
        int v = vec[id];
        int r = drev[v];
        int cl = child_l[n];
        int cr = child_r[n];
        int first  = r ? cr : cl;
        int second = r ? cl : cr;
        s_row0[t] = b * N_IN + first;
        s_row1[t] = b * N_IN + second;
    }
    __syncthreads();

    float acc[8][8];
    #pragma unroll
    for (int c = 0; c < 8; ++c)
        #pragma unroll
        for (int j = 0; j < 8; ++j) acc[c][j] = 0.f;

    const float* Wd = W + (size_t)dir * (2 * IDIM * ODIM);
    int ng = t >> 4;   // 0..15 -> nodes ng*8..ng*8+7
    int og = t & 15;   // 0..15 -> outputs og*8..og*8+7
    int ngs = ng & 3;  // swizzle key (same for all 8 rows of this thread)
    int aBase = (ng * 8) * 32;
    int wBase = og * 8 + ((og >> 1) << 2);   // skewed col base

    for (int kc = 0; kc < 8; ++kc) {
        int ks = kc * 32;                    // global K position 0..224
        int dim0 = ks & 127;
        const int* srow = (ks < 128) ? s_row0 : s_row1;
        // --- stage A: 128 rows x 32 floats; 2 threads/row, 16 floats each
        {
            int row = t >> 1;
            int rsrc = srow[row];
            #pragma unroll
            for (int j = 0; j < 4; ++j) {
                int cl4 = (t & 1) * 16 + j * 4;
                int chunk = (cl4 >> 2) ^ ((row >> 3) & 3);
                float4 v = *(const float4*)(last + (size_t)rsrc * IDIM + dim0 + cl4);
                *(float4*)&As[row * 32 + (chunk << 2)] = v;
            }
        }
        // --- stage W: 32 rows x 128 floats; 8 threads/row, 16 floats each
        {
            int row = t >> 3;
            const float* src = Wd + (size_t)(ks + row) * ODIM;
            #pragma unroll
            for (int j = 0; j < 4; ++j) {
                int c = (t & 7) * 16 + j * 4;
                float4 v = *(const float4*)(src + c);
                *(float4*)&Wl[w_ofs(row, c)] = v;
            }
        }
        __syncthreads();

        #pragma unroll 4
        for (int k = 0; k < BK; k += 4) {
            float4 a4[8];
            int aOf = aBase + (((k >> 2) ^ ngs) << 2);
            #pragma unroll
            for (int c = 0; c < 8; ++c)
                a4[c] = *(const float4*)&As[aOf + c * 32];
            #pragma unroll
            for (int kk = 0; kk < 4; ++kk) {
                float w[8];
                const float* wp = &Wl[(k + kk) * WSTRIDE + wBase];
                *(float4*)&w[0] = *(const float4*)&wp[0];
                *(float4*)&w[4] = *(const float4*)&wp[4];
                #pragma unroll
                for (int c = 0; c < 8; ++c) {
                    float av = (kk == 0) ? a4[c].x : (kk == 1) ? a4[c].y
                             : (kk == 2) ? a4[c].z : a4[c].w;
                    #pragma unroll
                    for (int j = 0; j < 8; ++j) acc[c][j] += av * w[j];
                }
            }
        }
        __syncthreads();
    }

    float alpha = alphap[0];
    float bb[8];
    *(float4*)&bb[0] = *(const float4*)&bias[dir * ODIM + og * 8];
    *(float4*)&bb[4] = *(const float4*)&bias[dir * ODIM + og * 8 + 4];
    int mBase = m0 + ng * 8;
    #pragma unroll
    for (int c = 0; c < 8; ++c) {
        int idx = mBase + c;
        if (idx >= end) break;
        int id = ids[idx];
        float ot[8];
        #pragma unroll
        for (int j = 0; j < 8; ++j) {
            float y = acc[c][j] + bb[j];
            ot[j] = y >= 0.f ? y : alpha * y;
        }
        float* op = out + (size_t)id * ODIM + og * 8;
        *(float4*)&op[0] = *(const float4*)&ot[0];
        *(float4*)&op[4] = *(const float4*)&ot[4];
    }
}

extern "C" void kernel_launch(void* const* d_in, const int* in_sizes, int n_in,
                              void* d_out, int out_size, void* d_ws, size_t ws_size,
                              hipStream_t stream) {
    const float* last    = (const float*)d_in[0];
    const float* W       = (const float*)d_in[1];
    const float* bias    = (const float*)d_in[2];
    const float* alpha   = (const float*)d_in[3];
    const int*   vec     = (const int*)d_in[4];
    const int*   dmap    = (const int*)d_in[5];
    const int*   drev    = (const int*)d_in[6];
    const int*   child_l = (const int*)d_in[7];
    const int*   child_r = (const int*)d_in[8];
    float* out = (float*)d_out;
    int*   ws  = (int*)d_ws;

    zero_kernel<<<1, 64, 0, stream>>>(ws);
    count_kernel<<<TOTAL / 256, 256, 0, stream>>>(vec, dmap, ws);
    prefix_kernel<<<1, 64, 0, stream>>>(ws);
    scatter_kernel<<<TOTAL / 256, 256, 0, stream>>>(vec, dmap, ws);
    dim3 grid(TOTAL / BM, NDIR);
    gemm_kernel<<<grid, 256, 0, stream>>>(last, W, bias, alpha, vec, drev,
                                          child_l, child_r, ws, out);
}

// Round 4
// 145.988 us; speedup vs baseline: 2.8763x; 2.8763x over previous
//
#include <hip/hip_runtime.h>

#define NDIR  6
#define B_    16
#define N_IN  16384
#define N_OUT 8192
#define IDIM  128
#define ODIM  128
#define TOTAL (B_ * N_OUT)   // 131072 nodes
#define BM    128            // nodes per block
#define BK    32             // K chunk (of 256)

// d_ws layout (ints): [0..7]=cnt, [8..14]=offsets, [16..23]=cursors, ids at 64
#define WS_CNT 0
#define WS_OFF 8
#define WS_CUR 16
#define WS_IDS 64

__global__ void zero_kernel(int* ws) {
    int t = threadIdx.x;
    if (t < 32) ws[t] = 0;
}

__global__ void count_kernel(const int* __restrict__ vec, const int* __restrict__ dmap,
                             int* __restrict__ ws) {
    __shared__ int h[NDIR];
    int t = threadIdx.x;
    if (t < NDIR) h[t] = 0;
    __syncthreads();
    int id = blockIdx.x * 256 + t;
    if (id < TOTAL) {
        int d = dmap[vec[id]];
        atomicAdd(&h[d], 1);
    }
    __syncthreads();
    if (t < NDIR && h[t]) atomicAdd(&ws[WS_CNT + t], h[t]);
}

__global__ void prefix_kernel(int* ws) {
    if (threadIdx.x == 0) {
        int acc = 0;
        for (int i = 0; i < NDIR; ++i) {
            ws[WS_OFF + i] = acc;
            ws[WS_CUR + i] = acc;
            acc += ws[WS_CNT + i];
        }
        ws[WS_OFF + NDIR] = acc;
    }
}

__global__ void scatter_kernel(const int* __restrict__ vec, const int* __restrict__ dmap,
                               int* __restrict__ ws) {
    __shared__ int h[NDIR];
    __shared__ int base[NDIR];
    int t = threadIdx.x;
    if (t < NDIR) h[t] = 0;
    __syncthreads();
    int id = blockIdx.x * 256 + t;
    int d = 0, pos = 0;
    if (id < TOTAL) {
        d = dmap[vec[id]];
        pos = atomicAdd(&h[d], 1);
    }
    __syncthreads();
    if (t < NDIR) base[t] = h[t] ? atomicAdd(&ws[WS_CUR + t], h[t]) : 0;
    __syncthreads();
    if (id < TOTAL) ws[WS_IDS + base[d] + pos] = id;
}

// A tile: [BM][32] floats, XOR-chunk swizzled: element (m,k) lives at
//   m*32 + (((k>>2) ^ ((m>>3)&3))<<2) + (k&3)
// Read (fixed c, 4 distinct ng per wave): keys ng&3 distinct -> 4 distinct
//   bank groups, 16-lane broadcast each: conflict-free.
// Write: lane->row permutation sigma (bits[1:0] <-> bits[4:3]) makes any
//   16-lane group carry keys {0,1,2,3}x2 with even/odd lanes differing in
//   chunk bit 2 -> 8 distinct bank groups x 2 lanes = 2-way = free.
// W tile: [32][164] floats with +4-float skew per 16 cols: (r,c) at
//   r*164 + c + ((c>>4)<<2)
// -> the 16 og-chunks cover each 4-bank group exactly twice: 2-way = free.
#define WSTRIDE 164
__device__ __forceinline__ int w_ofs(int r, int c) {
    return r * WSTRIDE + c + ((c >> 4) << 2);
}

__global__ __launch_bounds__(256, 2) void gemm_kernel(
    const float* __restrict__ last, const float* __restrict__ W,
    const float* __restrict__ bias, const float* __restrict__ alphap,
    const int* __restrict__ vec, const int* __restrict__ drev,
    const int* __restrict__ child_l, const int* __restrict__ child_r,
    const int* __restrict__ ws, float* __restrict__ out)
{
    int dir = blockIdx.y;
    int start = ws[WS_OFF + dir];
    int end   = ws[WS_OFF + dir + 1];
    int m0 = start + (int)blockIdx.x * BM;
    if (m0 >= end) return;
    const int* ids = ws + WS_IDS;

    __shared__ int   s_row0[BM], s_row1[BM];
    __shared__ float As[BM * 32];
    __shared__ float Wl[BK * WSTRIDE];

    int t = threadIdx.x;
    if (t < BM) {
        int idx = m0 + t;
        bool valid = idx < end;
        int id = ids[valid ? idx : end - 1];
        int b = id >> 13;            // N_OUT = 8192
        int n = id & (N_OUT - 1);
        int v = vec[id];
        int r = drev[v];
        int cl = child_l[n];
        int cr = child_r[n];
        int first  = r ? cr : cl;
        int second = r ? cl : cr;
        s_row0[t] = b * N_IN + first;
        s_row1[t] = b * N_IN + second;
    }
    __syncthreads();

    float acc[8][8];
    #pragma unroll
    for (int c = 0; c < 8; ++c)
        #pragma unroll
        for (int j = 0; j < 8; ++j) acc[c][j] = 0.f;

    const float* Wd = W + (size_t)dir * (2 * IDIM * ODIM);
    int ng = t >> 4;   // 0..15 -> nodes ng*8..ng*8+7
    int og = t & 15;   // 0..15 -> outputs og*8..og*8+7
    int ngs = ng & 3;  // A swizzle key (read side)
    int aBase = (ng * 8) * 32;
    int wBase = og * 8 + ((og >> 1) << 2);   // skewed col base

    // A-stage lane->row permutation: swap bits[1:0] with bits[4:3] of u=t>>1
    int u = t >> 1, p = t & 1;
    int arow = (u & 0x64) | ((u & 3) << 3) | ((u >> 3) & 3);
    int akey = (arow >> 3) & 3;

    for (int kc = 0; kc < 8; ++kc) {
        int ks = kc * 32;                    // global K position 0..224
        int dim0 = ks & 127;
        const int* srow = (ks < 128) ? s_row0 : s_row1;
        // --- stage A: 128 rows x 32 floats; 2 threads/row (permuted), 16B x4
        {
            int rsrc = srow[arow];
            #pragma unroll
            for (int j = 0; j < 4; ++j) {
                int cl4 = p * 16 + j * 4;
                int chunk = (cl4 >> 2) ^ akey;
                float4 v = *(const float4*)(last + (size_t)rsrc * IDIM + dim0 + cl4);
                *(float4*)&As[arow * 32 + (chunk << 2)] = v;
            }
        }
        // --- stage W: 32 rows x 128 floats; 8 threads/row, 16 floats each
        {
            int row = t >> 3;
            const float* src = Wd + (size_t)(ks + row) * ODIM;
            #pragma unroll
            for (int j = 0; j < 4; ++j) {
                int c = (t & 7) * 16 + j * 4;
                float4 v = *(const float4*)(src + c);
                *(float4*)&Wl[w_ofs(row, c)] = v;
            }
        }
        __syncthreads();

        #pragma unroll 4
        for (int k = 0; k < BK; k += 4) {
            float4 a4[8];
            int aOf = aBase + (((k >> 2) ^ ngs) << 2);
            #pragma unroll
            for (int c = 0; c < 8; ++c)
                a4[c] = *(const float4*)&As[aOf + c * 32];
            #pragma unroll
            for (int kk = 0; kk < 4; ++kk) {
                float w[8];
                const float* wp = &Wl[(k + kk) * WSTRIDE + wBase];
                *(float4*)&w[0] = *(const float4*)&wp[0];
                *(float4*)&w[4] = *(const float4*)&wp[4];
                #pragma unroll
                for (int c = 0; c < 8; ++c) {
                    float av = (kk == 0) ? a4[c].x : (kk == 1) ? a4[c].y
                             : (kk == 2) ? a4[c].z : a4[c].w;
                    #pragma unroll
                    for (int j = 0; j < 8; ++j) acc[c][j] += av * w[j];
                }
            }
        }
        __syncthreads();
    }

    float alpha = alphap[0];
    float bb[8];
    *(float4*)&bb[0] = *(const float4*)&bias[dir * ODIM + og * 8];
    *(float4*)&bb[4] = *(const float4*)&bias[dir * ODIM + og * 8 + 4];
    int mBase = m0 + ng * 8;
    #pragma unroll
    for (int c = 0; c < 8; ++c) {
        int idx = mBase + c;
        if (idx >= end) break;
        int id = ids[idx];
        float ot[8];
        #pragma unroll
        for (int j = 0; j < 8; ++j) {
            float y = acc[c][j] + bb[j];
            ot[j] = y >= 0.f ? y : alpha * y;
        }
        float* op = out + (size_t)id * ODIM + og * 8;
        *(float4*)&op[0] = *(const float4*)&ot[0];
        *(float4*)&op[4] = *(const float4*)&ot[4];
    }
}

extern "C" void kernel_launch(void* const* d_in, const int* in_sizes, int n_in,
                              void* d_out, int out_size, void* d_ws, size_t ws_size,
                              hipStream_t stream) {
    const float* last    = (const float*)d_in[0];
    const float* W       = (const float*)d_in[1];
    const float* bias    = (const float*)d_in[2];
    const float* alpha   = (const float*)d_in[3];
    const int*   vec     = (const int*)d_in[4];
    const int*   dmap    = (const int*)d_in[5];
    const int*   drev    = (const int*)d_in[6];
    const int*   child_l = (const int*)d_in[7];
    const int*   child_r = (const int*)d_in[8];
    float* out = (float*)d_out;
    int*   ws  = (int*)d_ws;

    zero_kernel<<<1, 64, 0, stream>>>(ws);
    count_kernel<<<TOTAL / 256, 256, 0, stream>>>(vec, dmap, ws);
    prefix_kernel<<<1, 64, 0, stream>>>(ws);
    scatter_kernel<<<TOTAL / 256, 256, 0, stream>>>(vec, dmap, ws);
    dim3 grid(TOTAL / BM, NDIR);
    gemm_kernel<<<grid, 256, 0, stream>>>(last, W, bias, alpha, vec, drev,
                                          child_l, child_r, ws, out);
}

// Round 5
// 100.167 us; speedup vs baseline: 4.1920x; 1.4574x over previous
//
#include <hip/hip_runtime.h>

#define NDIR  6
#define B_    16
#define N_IN  16384
#define N_OUT 8192
#define IDIM  128
#define ODIM  128
#define TOTAL (B_ * N_OUT)   // 131072 nodes
#define BM    128            // nodes per block (4 waves x 32 rows)

// d_ws layout (ints): [0..7]=cnt, [8..14]=offsets, [16..23]=cursors,
// ids at int 64 (131072 ints), Wt (bf16 hi/lo, pre-swizzled) at int 131584.
#define WS_CNT 0
#define WS_OFF 8
#define WS_CUR 16
#define WS_IDS 64
#define WS_WT  131584

using s16x8 = __attribute__((ext_vector_type(8))) short;   // 8 bf16 (4 VGPR)
using f32x4 = __attribute__((ext_vector_type(4))) float;   // acc frag

__global__ void zero_kernel(int* ws) {
    int t = threadIdx.x;
    if (t < 32) ws[t] = 0;
}

__global__ void count_kernel(const int* __restrict__ vec, const int* __restrict__ dmap,
                             int* __restrict__ ws) {
    __shared__ int h[NDIR];
    int t = threadIdx.x;
    if (t < NDIR) h[t] = 0;
    __syncthreads();
    int id = blockIdx.x * 256 + t;
    if (id < TOTAL) {
        int d = dmap[vec[id]];
        atomicAdd(&h[d], 1);
    }
    __syncthreads();
    if (t < NDIR && h[t]) atomicAdd(&ws[WS_CNT + t], h[t]);
}

__global__ void prefix_kernel(int* ws) {
    if (threadIdx.x == 0) {
        int acc = 0;
        for (int i = 0; i < NDIR; ++i) {
            ws[WS_OFF + i] = acc;
            ws[WS_CUR + i] = acc;
            acc += ws[WS_CNT + i];
        }
        ws[WS_OFF + NDIR] = acc;
    }
}

__global__ void scatter_kernel(const int* __restrict__ vec, const int* __restrict__ dmap,
                               int* __restrict__ ws) {
    __shared__ int h[NDIR];
    __shared__ int base[NDIR];
    int t = threadIdx.x;
    if (t < NDIR) h[t] = 0;
    __syncthreads();
    int id = blockIdx.x * 256 + t;
    int d = 0, pos = 0;
    if (id < TOTAL) {
        d = dmap[vec[id]];
        pos = atomicAdd(&h[d], 1);
    }
    __syncthreads();
    if (t < NDIR) base[t] = h[t] ? atomicAdd(&ws[WS_CUR + t], h[t]) : 0;
    __syncthreads();
    if (id < TOTAL) ws[WS_IDS + base[d] + pos] = id;
}

// Pre-transpose + bf16-split + swizzle W into d_ws.
// Per (dir d, kstep s): 16KB block = hi[col 0..127][chunk' 0..3][i 0..7] bf16
// (8KB) then lo (8KB). Stored chunk position c' holds source chunk c'^key,
// key(col) = (col>>1)&3. So a ds_read at c' = (l>>4)^key returns k-chunk l>>4.
__global__ void wconvert_kernel(const float* __restrict__ W, int* __restrict__ ws) {
    unsigned short* wt = (unsigned short*)(ws + WS_WT);
    int g = blockIdx.x * 256 + threadIdx.x;      // 0..196607
    int dsb = g >> 12;                           // d*8+s, 0..47
    int e = g & 4095;
    int col = e >> 5;
    int kk = e & 31;
    int cp = kk >> 3, i = kk & 7;
    int key = (col >> 1) & 3;
    int d = dsb >> 3, s = dsb & 7;
    int ksrc = s * 32 + ((cp ^ key) << 3) + i;
    float w = W[((d * 256) + ksrc) * 128 + col];
    unsigned u = __float_as_uint(w);
    float hf = __uint_as_float(u & 0xFFFF0000u);
    float lf = w - hf;
    int base = dsb * 8192 + col * 32 + cp * 8 + i;
    wt[base] = (unsigned short)(u >> 16);
    wt[base + 4096] = (unsigned short)(__float_as_uint(lf) >> 16);
}

__device__ __forceinline__ void cvt8(float4 a, float4 b, s16x8& h, s16x8& lo) {
    float x[8] = {a.x, a.y, a.z, a.w, b.x, b.y, b.z, b.w};
    #pragma unroll
    for (int j = 0; j < 8; ++j) {
        unsigned u = __float_as_uint(x[j]);
        float hf = __uint_as_float(u & 0xFFFF0000u);
        float lf = x[j] - hf;
        h[j] = (short)(u >> 16);
        lo[j] = (short)(__float_as_uint(lf) >> 16);
    }
}

// MFMA gather-GEMM: block = 128 nodes x 128 outputs, 4 waves (32 rows each),
// K=256 in 8 steps of 32. fp32 via 3x bf16 MFMA (hh + hl + lh).
__global__ __launch_bounds__(256, 2) void gemm_kernel(
    const float* __restrict__ last, const float* __restrict__ bias,
    const float* __restrict__ alphap,
    const int* __restrict__ vec, const int* __restrict__ drev,
    const int* __restrict__ child_l, const int* __restrict__ child_r,
    const int* __restrict__ ws, float* __restrict__ out)
{
    int dir = blockIdx.y;
    int start = ws[WS_OFF + dir];
    int end   = ws[WS_OFF + dir + 1];
    int m0 = start + (int)blockIdx.x * BM;
    if (m0 >= end) return;
    const int* ids = ws + WS_IDS;

    __shared__ unsigned short wbuf[2][8192];   // 2 x 16KB W tiles
    __shared__ int s_row0[BM], s_row1[BM], s_oid[BM];

    int t = threadIdx.x;
    int l = t & 63;
    int wid = t >> 6;

    if (t < BM) {
        int idx = m0 + t;
        bool valid = idx < end;
        int id = ids[valid ? idx : end - 1];
        int b = id >> 13;            // N_OUT = 8192
        int n = id & (N_OUT - 1);
        int v = vec[id];
        int r = drev[v];
        int cl = child_l[n];
        int cr = child_r[n];
        int first  = r ? cr : cl;
        int second = r ? cl : cr;
        s_row0[t] = b * N_IN + first;
        s_row1[t] = b * N_IN + second;
        s_oid[t]  = valid ? id : -1;
    }

    const char* wt_blk = (const char*)(ws + WS_WT) + (size_t)dir * 8 * 16384;

    // stage W kstep `s` into wbuf[buf]: wave wid copies bytes [wid*4K, +4K)
    // as 4 x global_load_lds(16B/lane); LDS dest wave-uniform, linear.
    #define STAGE_W(buf, s_)                                                     \
        {                                                                        \
            const char* gsrc = wt_blk + (size_t)(s_) * 16384 + wid * 4096 + l * 16; \
            char* ldst = (char*)&wbuf[buf][0] + wid * 4096;                      \
            _Pragma("unroll")                                                    \
            for (int i_ = 0; i_ < 4; ++i_) {                                     \
                __builtin_amdgcn_global_load_lds(                                \
                    (const __attribute__((address_space(1))) void*)(gsrc + i_ * 1024), \
                    (__attribute__((address_space(3))) void*)(ldst + i_ * 1024), \
                    16, 0, 0);                                                   \
            }                                                                    \
        }

    STAGE_W(0, 0);
    __syncthreads();   // row-prep + stage(0) visible

    f32x4 acc[2][8];
    #pragma unroll
    for (int f = 0; f < 2; ++f)
        #pragma unroll
        for (int nf = 0; nf < 8; ++nf)
            acc[f][nf] = (f32x4){0.f, 0.f, 0.f, 0.f};

    #pragma unroll
    for (int s = 0; s < 8; ++s) {
        int cur = s & 1;
        // --- A: global -> reg -> bf16 hi/lo (each element used by 1 lane only)
        s16x8 ah[2], al[2];
        #pragma unroll
        for (int f = 0; f < 2; ++f) {
            int m = wid * 32 + f * 16 + (l & 15);
            int r = (s < 4) ? s_row0[m] : s_row1[m];
            const float* src = last + (size_t)r * IDIM + (s & 3) * 32 + (l >> 4) * 8;
            float4 x0 = *(const float4*)src;
            float4 x1 = *(const float4*)(src + 4);
            cvt8(x0, x1, ah[f], al[f]);
        }
        // --- prefetch next W tile (overwrites buffer last read 2 steps ago)
        if (s < 7) STAGE_W(cur ^ 1, s + 1);
        // --- B frags from LDS (swizzled: 2-way max = free)
        s16x8 bh[8], bl[8];
        #pragma unroll
        for (int nf = 0; nf < 8; ++nf) {
            int col = nf * 16 + (l & 15);
            int cp = (l >> 4) ^ ((col >> 1) & 3);
            int off = col * 32 + cp * 8;          // shorts
            bh[nf] = *(const s16x8*)&wbuf[cur][off];
            bl[nf] = *(const s16x8*)&wbuf[cur][off + 4096];
        }
        // --- 3-term split MFMA: 16 frags x 3
        #pragma unroll
        for (int f = 0; f < 2; ++f) {
            #pragma unroll
            for (int nf = 0; nf < 8; ++nf) {
                acc[f][nf] = __builtin_amdgcn_mfma_f32_16x16x32_bf16(ah[f], bh[nf], acc[f][nf], 0, 0, 0);
                acc[f][nf] = __builtin_amdgcn_mfma_f32_16x16x32_bf16(ah[f], bl[nf], acc[f][nf], 0, 0, 0);
                acc[f][nf] = __builtin_amdgcn_mfma_f32_16x16x32_bf16(al[f], bh[nf], acc[f][nf], 0, 0, 0);
            }
        }
        __syncthreads();   // drains stage(next); orders buffer reuse
    }

    // --- epilogue: D frag row=(l>>4)*4+j, col=l&15 (m89/m91 verified)
    float alpha = alphap[0];
    #pragma unroll
    for (int nf = 0; nf < 8; ++nf) {
        int col = nf * 16 + (l & 15);
        float bv = bias[dir * ODIM + col];
        #pragma unroll
        for (int f = 0; f < 2; ++f) {
            #pragma unroll
            for (int j = 0; j < 4; ++j) {
                int mloc = wid * 32 + f * 16 + (l >> 4) * 4 + j;
                int id = s_oid[mloc];
                if (id < 0) continue;
                float y = acc[f][nf][j] + bv;
                out[(size_t)id * ODIM + col] = y >= 0.f ? y : alpha * y;
            }
        }
    }
    #undef STAGE_W
}

extern "C" void kernel_launch(void* const* d_in, const int* in_sizes, int n_in,
                              void* d_out, int out_size, void* d_ws, size_t ws_size,
                              hipStream_t stream) {
    const float* last    = (const float*)d_in[0];
    const float* W       = (const float*)d_in[1];
    const float* bias    = (const float*)d_in[2];
    const float* alpha   = (const float*)d_in[3];
    const int*   vec     = (const int*)d_in[4];
    const int*   dmap    = (const int*)d_in[5];
    const int*   drev    = (const int*)d_in[6];
    const int*   child_l = (const int*)d_in[7];
    const int*   child_r = (const int*)d_in[8];
    float* out = (float*)d_out;
    int*   ws  = (int*)d_ws;

    zero_kernel<<<1, 64, 0, stream>>>(ws);
    count_kernel<<<TOTAL / 256, 256, 0, stream>>>(vec, dmap, ws);
    prefix_kernel<<<1, 64, 0, stream>>>(ws);
    scatter_kernel<<<TOTAL / 256, 256, 0, stream>>>(vec, dmap, ws);
    wconvert_kernel<<<(NDIR * 8 * 4096) / 256, 256, 0, stream>>>(W, ws);
    dim3 grid(TOTAL / BM, NDIR);
    gemm_kernel<<<grid, 256, 0, stream>>>(last, bias, alpha, vec, drev,
                                          child_l, child_r, ws, out);
}